// Round 6
// baseline (357.455 us; speedup 1.0000x reference)
//
#include <hip/hip_runtime.h>
#include <hip/hip_bf16.h>

// MultiScaleRetention forward. Inputs/outputs FLOAT32; internals bf16 MFMA.
//   0) convert x -> xb (bf16); transpose weights f32 -> bf16
//   1) GEMM1 (m97-style, global_load_lds staging): xb @ Wt^T; LEAN epilogue,
//      ALL-COALESCED: qk -> f32 Cqk (+bias,+k-scale); v -> bf16 vbuf; g -> f32
//   2) vtrans: vbuf (b, s, 2048) -> vf FRAGMENT layout [bh][nt][dt][lane]x16B
//      (R15-proven)
//   3) router: rotary (f32) + hi/lo bf16 split; q -> (bh,S,64); k -> FRAGMENT
//      layout chunk=(bh*64+nt)*8+hl*4+hh*2+dh, lane element = lane*8
//      (same values the R12/R15 LDS path delivered, traced lane-by-lane)
//   4) retention R16 = R15 with K ALSO direct global->registers from the
//      fragment buffer: ZERO LDS, ZERO barriers, zero explicit waitcnt.
//      Grid/pairing/math identical to R15 (1024 blocks x 2 waves, paired
//      32-row half-stripes, swapped QK + permlane P, V direct). K ping-pong
//      double-buffered (8 x global_load_dwordx4/tile). Compiler emits
//      counted vmcnt; waves free-run. K/V values + FP order bit-identical
//      to R15 -> absmax must stay exactly 0.01049805 (canary).
//      Bisect logic: V-frag path proven by R15; if R16 NaNs the router
//      K-frag layout is condemned; if it passes, R13's NaN was its grid
//      restructure (moot).
//   5) GEMM2: gated @ oT^T + o_b -> d_out (f32)

typedef __hip_bfloat16 bf16;
typedef short bf16x4 __attribute__((ext_vector_type(4)));
typedef short bf16x8 __attribute__((ext_vector_type(8)));
typedef float floatx4 __attribute__((ext_vector_type(4)));

#define B_SZ 2
#define SEQ 2048
#define NH 16
#define KD 64
#define HD 128

// global->LDS direct copy, 16B/lane. LDS dest is wave-uniform base + lane*16.
#define ASYNC16(gp, lp)                                                             \
  __builtin_amdgcn_global_load_lds(                                                 \
      (const __attribute__((address_space(1))) unsigned int*)(unsigned long long)(const void*)(gp), \
      (__attribute__((address_space(3))) unsigned int*)(unsigned int)(unsigned long long)(void*)(lp), \
      16, 0, 0)

__device__ __forceinline__ float b2f(bf16 x) { return __bfloat162float(x); }
__device__ __forceinline__ bf16 f2b(float x) { return __float2bfloat16(x); }

#define MFMA16(a, bb, c) __builtin_amdgcn_mfma_f32_16x16x32_bf16(a, bb, c, 0, 0, 0)

// ---------------- f32 -> bf16 convert (x) ----------------
__global__ void convert_k(const float* __restrict__ in, bf16* __restrict__ out) {
  int i = blockIdx.x * 256 + threadIdx.x;  // one float4 per thread
  float4 v = reinterpret_cast<const float4*>(in)[i];
  union { bf16 h[4]; bf16x4 v4; } u;
  u.h[0] = f2b(v.x); u.h[1] = f2b(v.y); u.h[2] = f2b(v.z); u.h[3] = f2b(v.w);
  reinterpret_cast<bf16x4*>(out)[i] = u.v4;
}

// ---------------- weight transpose: in f32 (K,N) -> out bf16 (N,K) --------
__global__ void transpose_k(const float* __restrict__ in, bf16* __restrict__ out,
                            int K, int N) {
  __shared__ float tile[32][33];
  int tx = threadIdx.x, ty = threadIdx.y;
  int n0 = blockIdx.x * 32, k0 = blockIdx.y * 32;
#pragma unroll
  for (int j = 0; j < 4; ++j)
    tile[ty + j * 8][tx] = in[(size_t)(k0 + ty + j * 8) * N + n0 + tx];
  __syncthreads();
#pragma unroll
  for (int j = 0; j < 4; ++j)
    out[(size_t)(n0 + ty + j * 8) * K + k0 + tx] = f2b(tile[tx][ty + j * 8]);
}

// ---------------- v transpose -> V fragment layout (R15-proven) ----------
// chunk = (bh*64 + nt)*8 + dt; lane = quad*16 + l16 holds
// V[d = dt*16+l16][s = nt*32 + quad*8 + j], j=0..7.
__global__ void vtrans_k(const bf16* __restrict__ in, bf16* __restrict__ out) {
  __shared__ bf16 tile[32][72];
  int tx = threadIdx.x, ty = threadIdx.y;  // (32,8)
  int s0 = blockIdx.x * 32, c0 = blockIdx.y * 64, bz = blockIdx.z;
  const bf16* src = in + (size_t)bz * 2048 * 2048;
#pragma unroll
  for (int j = 0; j < 4; ++j) {
    int sr = ty + j * 8;
    tile[sr][tx] = src[(size_t)(s0 + sr) * 2048 + c0 + tx];
    tile[sr][tx + 32] = src[(size_t)(s0 + sr) * 2048 + c0 + 32 + tx];
  }
  __syncthreads();
  int tid = ty * 32 + tx;
  int dl = tid & 63, srun = tid >> 6;
  int c = c0 + dl, hh = c >> 7, d = c & 127;
  int dt = d >> 4, lw = d & 15;
  union { bf16 e[8]; bf16x8 v; } pk;
#pragma unroll
  for (int k = 0; k < 8; ++k) pk.e[k] = tile[srun * 8 + k][dl];
  size_t bh = (size_t)bz * NH + hh;
  int nt = s0 >> 5;
  size_t idx = ((bh * 64 + nt) * 8 + dt) * 512 + (size_t)(srun * 16 + lw) * 8;
  *(bf16x8*)&out[idx] = pk.v;
}

// ---------------- GEMM: C(M,N) = A(M,K) @ Bt(N,K)^T ----------------
template <int BM, int BN, int KDIM, int MODE>
__global__ __launch_bounds__(256, 2) void gemm_bt(
    const bf16* __restrict__ A, const bf16* __restrict__ Bt, int Ndim,
    const float* __restrict__ bias_q, const float* __restrict__ bias_k,
    const float* __restrict__ bias_v, const float* __restrict__ bias_g,
    float* __restrict__ outCqk, bf16* __restrict__ out_v,
    float* __restrict__ out_g, float* __restrict__ outF) {
  __shared__ bf16 As[BM * 32];
  __shared__ bf16 Bs[BN * 32];
  const int tid = threadIdx.x;
  const int wave = tid >> 6, lane = tid & 63;
  const int quad = lane >> 4, l16 = lane & 15;
  const int m0 = blockIdx.y * BM, n0 = blockIdx.x * BN;
  constexpr int FI = BM / 32;
  constexpr int FJ = BN / 32;
  const int wm = (wave >> 1) * (BM / 2), wn = (wave & 1) * (BN / 2);

  floatx4 acc[FI][FJ] = {};

  for (int k0 = 0; k0 < KDIM; k0 += 32) {
#pragma unroll
    for (int j = 0; j < BM / 64; ++j) {
      int cbase = (j * 4 + wave) * 64;
      int c = cbase + lane;
      const bf16* g = A + (size_t)(m0 + (c >> 2)) * KDIM + k0 + (c & 3) * 8;
      ASYNC16(g, &As[cbase * 8]);
    }
#pragma unroll
    for (int j = 0; j < BN / 64; ++j) {
      int cbase = (j * 4 + wave) * 64;
      int c = cbase + lane;
      const bf16* g = Bt + (size_t)(n0 + (c >> 2)) * KDIM + k0 + (c & 3) * 8;
      ASYNC16(g, &Bs[cbase * 8]);
    }
    __syncthreads();  // compiler drains vmcnt(0) before s_barrier

    bf16x8 af[FI], bfr[FJ];
#pragma unroll
    for (int i = 0; i < FI; ++i)
      af[i] = *(const bf16x8*)&As[(wm + i * 16 + l16) * 32 + quad * 8];
#pragma unroll
    for (int j = 0; j < FJ; ++j)
      bfr[j] = *(const bf16x8*)&Bs[(wn + j * 16 + l16) * 32 + quad * 8];
#pragma unroll
    for (int i = 0; i < FI; ++i)
#pragma unroll
      for (int j = 0; j < FJ; ++j)
        acc[i][j] = MFMA16(af[i], bfr[j], acc[i][j]);
    __syncthreads();
  }

  // LEAN epilogue, all stores coalesced
#pragma unroll
  for (int i = 0; i < FI; ++i) {
#pragma unroll
    for (int j = 0; j < FJ; ++j) {
#pragma unroll
      for (int r = 0; r < 4; ++r) {
        int gm = m0 + wm + i * 16 + quad * 4 + r;
        int gn = n0 + wn + j * 16 + l16;
        float v = acc[i][j][r];
        if (MODE == 1) {
          v += bias_q[gn];  // bias_q = o_b
          outF[(size_t)gm * Ndim + gn] = v;
        } else {
          if (gn < 2048) {
            bool is_k = gn >= 1024;
            int jj = is_k ? gn - 1024 : gn;
            v += is_k ? bias_k[jj] : bias_q[jj];
            if (is_k) v *= 0.125f;  // SCALING = KEY_DIM^-0.5
            outCqk[(size_t)gm * 2048 + gn] = v;  // f32, exact
          } else if (gn < 4096) {
            int jj = gn - 2048;
            v += bias_v[jj];
            out_v[(size_t)gm * 2048 + jj] = f2b(v);  // natural layout
          } else {
            int jj = gn - 4096;
            v += bias_g[jj];
            out_g[(size_t)gm * 2048 + jj] = v;  // f32
          }
        }
      }
    }
  }
}

// ---------------- router: rotary + hi/lo split + layouts ----------------
// q -> (bh, s, 64). k -> fragment layout: chunk (bh*64+nt)*8 + hl*4+hh*2+dh;
// lane = quad*16+l16 holds K[s = nt*32+hh*16+l16][d = dh*32+quad*8+j].
__global__ void router_k(const float* __restrict__ Cqk,
                         bf16* __restrict__ qh, bf16* __restrict__ ql,
                         bf16* __restrict__ kf) {
  int t = blockIdx.x * 256 + threadIdx.x;  // 4096*1024 threads
  int row = t >> 10, pc = t & 1023;
  int b = row >> 11, s = row & 2047;
  bool is_k = pc >= 512;
  int jj = (pc - (is_k ? 512 : 0)) * 2;  // even, 0..1022
  int h = jj >> 6, d = jj & 63, ii = d >> 1;
  float2 v = *(const float2*)&Cqk[(size_t)row * 2048 + pc * 2];
  float half = exp2f(-(float)ii * (13.287712379549449f / 31.0f));
  float ang = (float)s * half;
  float sn = sinf(ang), cs = cosf(ang);
  float e = v.x * cs - v.y * sn;
  float o = v.y * cs + v.x * sn;
  bf16 eh = f2b(e), oh = f2b(o);
  bf16 el = f2b(e - b2f(eh)), ol = f2b(o - b2f(oh));
  union { bf16 h2[2]; unsigned u; } uh, ul;
  uh.h2[0] = eh; uh.h2[1] = oh;
  ul.h2[0] = el; ul.h2[1] = ol;
  size_t bh = (size_t)b * NH + h;
  if (!is_k) {
    size_t idx = (bh * SEQ + s) * KD + d;
    *(unsigned*)&qh[idx] = uh.u;
    *(unsigned*)&ql[idx] = ul.u;
  } else {
    int nt = s >> 5, hh = (s >> 4) & 1, lr = s & 15;
    int dh = d >> 5, qd = (d >> 3) & 3, jb = d & 7;
    size_t cbase = ((bh * 64 + nt) * 8);
    size_t off = (size_t)(qd * 16 + lr) * 8 + jb;
    *(unsigned*)&kf[(cbase + hh * 2 + dh) * 512 + off] = uh.u;      // hi
    *(unsigned*)&kf[(cbase + 4 + hh * 2 + dh) * 512 + off] = ul.u;  // lo
  }
}

// ---------------- retention core (R16: zero-LDS, zero-barrier) ----------
// Grid/pairing IDENTICAL to R15: 1024 blocks x 128 threads; seg = bid>>5,
// h=seg&15, b=seg>>4, px = (seg bit3) ? 31-(bid&31) : bid&31. Block owns
// heavy half-stripe bt_h=63-px and light bt_l=px (32 rows each; each wave
// a 16-row stripe). K ping-pong double-buffered in regs; V loaded per-tile.
// No LDS, no barriers -> waves free-run, compiler counts vmcnt.
__global__ __launch_bounds__(128, 2) void retention_k(
    const bf16* __restrict__ qh, const bf16* __restrict__ ql,
    const bf16* __restrict__ kf, const bf16* __restrict__ vf,
    const float* __restrict__ g, bf16* __restrict__ gated) {
  const int tid = threadIdx.x;
  const int wave = tid >> 6, lane = tid & 63;
  const int quad = lane >> 4, l16 = lane & 15;
  const int bid = blockIdx.x;
  const int px_raw = bid & 31;
  const int seg = bid >> 5;           // 0..31
  const int h = seg & 15, b = seg >> 4;
  const int px = ((seg >> 3) & 1) ? (31 - px_raw) : px_raw;
  const int bh = b * NH + h;
  const int bt_h = 63 - px;           // heavy half-stripe (32 rows)
  const int bt_l = px;                // light half-stripe
  const int m0h = bt_h * 32 + wave * 16;
  const int m0l = bt_l * 32 + wave * 16;
  const int ntiles = bt_h + 1;
  const int lt_ntiles = bt_l + 1;

  const float t = exp2f(-(float)(5 + h));  // 1-gamma (exact)
  const float lng = log1pf(-t);            // ln(gamma)
  const float log2g = lng * 1.44269504088896340736f;

  // per-lane row scalars (m = m0 + l16)
  float rfh, rfl;
  {
    int mh = m0h + l16, ml = m0l + l16;
    rfh = exp2f((float)mh * log2g) *
          rsqrtf(-expm1f((float)(mh + 1) * lng) / t);
    rfl = exp2f((float)ml * log2g) *
          rsqrtf(-expm1f((float)(ml + 1) * lng) / t);
  }
  const float gstep = exp2f(-32.0f * log2g);  // gamma^-32
  // per-lane col decay: n-offset = hh*16 + quad*4 + r
  float cfq[8];
#pragma unroll
  for (int i = 0; i < 8; ++i) {
    int hh = i >> 2, r = i & 3;
    cfq[i] = exp2f(-(float)(hh * 16 + quad * 4 + r) * log2g);
  }

  const size_t qoffh = ((size_t)bh * SEQ + m0h + l16) * KD;
  const size_t qoffl = ((size_t)bh * SEQ + m0l + l16) * KD;
  bf16x8 aq0h_h = *(const bf16x8*)&qh[qoffh + quad * 8];
  bf16x8 aq1h_h = *(const bf16x8*)&qh[qoffh + 32 + quad * 8];
  bf16x8 aq0l_h = *(const bf16x8*)&ql[qoffh + quad * 8];
  bf16x8 aq1l_h = *(const bf16x8*)&ql[qoffh + 32 + quad * 8];
  bf16x8 aq0h_l = *(const bf16x8*)&qh[qoffl + quad * 8];
  bf16x8 aq1h_l = *(const bf16x8*)&qh[qoffl + 32 + quad * 8];
  bf16x8 aq0l_l = *(const bf16x8*)&ql[qoffl + quad * 8];
  bf16x8 aq1l_l = *(const bf16x8*)&ql[qoffl + 32 + quad * 8];

  floatx4 oacch[8] = {}, oaccl[8] = {};
  float rsh = 0.f, rsl = 0.f;

  const bf16* kfb = kf + (size_t)bh * 64 * 8 * 512;
  const bf16* vfb = vf + (size_t)bh * 64 * 8 * 512;
  const int lo8 = lane * 8;

  bf16x8 kA[8], kB[8];
  auto loadK = [&](bf16x8 (&d)[8], int nt_) {
#pragma unroll
    for (int c = 0; c < 8; ++c)
      d[c] = *(const bf16x8*)(kfb + ((size_t)nt_ * 8 + c) * 512 + lo8);
  };

  // Build PV A-frag in-register from the transposed score tile (as R12/R15).
  auto buildPA = [&](const floatx4* sc, float rf, float& rs, int n0,
                     int m0) -> bf16x8 {
    const int m = m0 + l16;
    const bool full = (m0 >= n0 + 31);  // tile fully below diagonal
    unsigned d[4];
#pragma unroll
    for (int hh = 0; hh < 2; ++hh) {
      float p[4];
#pragma unroll
      for (int r = 0; r < 4; ++r) {
        float pv;
        if (full) {
          pv = sc[hh][r] * rf * cfq[hh * 4 + r];
        } else {
          int n = n0 + hh * 16 + quad * 4 + r;
          pv = (m >= n) ? sc[hh][r] * rf * cfq[hh * 4 + r] : 0.f;
        }
        rs += pv;
        p[r] = pv;
      }
      union { bf16 hx[2]; unsigned u; } u0, u1;
      u0.hx[0] = f2b(p[0]); u0.hx[1] = f2b(p[1]);
      u1.hx[0] = f2b(p[2]); u1.hx[1] = f2b(p[3]);
      d[hh * 2 + 0] = u0.u;
      d[hh * 2 + 1] = u1.u;
    }
    unsigned a0 = d[0], b0 = d[2];  // (hh0 pair01, hh1 pair01)
    asm("v_permlane32_swap_b32 %0, %1" : "+v"(a0), "+v"(b0));
    asm("v_permlane16_swap_b32 %0, %1" : "+v"(a0), "+v"(b0));
    unsigned a1 = d[1], b1 = d[3];  // (hh0 pair23, hh1 pair23)
    asm("v_permlane32_swap_b32 %0, %1" : "+v"(a1), "+v"(b1));
    asm("v_permlane16_swap_b32 %0, %1" : "+v"(a1), "+v"(b1));
    union { unsigned u[4]; bf16x8 v; } pu;
    pu.u[0] = a0; pu.u[1] = a1; pu.u[2] = b0; pu.u[3] = b1;
    return pu.v;
  };

  auto body = [&](bf16x8 (&k)[8], int nt) {
    const int n0 = nt * 32;
    // V tile direct to registers; loads issue here, consumed by PV after
    // QK/buildPA -> latency hidden, compiler counts vmcnt.
    bf16x8 vv[8];
#pragma unroll
    for (int c = 0; c < 8; ++c)
      vv[c] = *(const bf16x8*)(vfb + ((size_t)nt * 8 + c) * 512 + lo8);

    const bool hact = (n0 <= m0h + 15);
    const bool lact = (n0 <= m0l + 15);

    floatx4 sch[2], scl[2];
#pragma unroll
    for (int hh = 0; hh < 2; ++hh) {
      bf16x8 bkh0 = k[hh * 2 + 0], bkh1 = k[hh * 2 + 1];
      bf16x8 bkl0 = k[4 + hh * 2 + 0], bkl1 = k[4 + hh * 2 + 1];
      if (hact) {
        floatx4 z1 = {0.f, 0.f, 0.f, 0.f}, z2 = z1, z3 = z1;
        z1 = MFMA16(bkh0, aq0h_h, z1);
        z2 = MFMA16(bkh0, aq0l_h, z2);
        z3 = MFMA16(bkl0, aq0h_h, z3);
        z1 = MFMA16(bkh1, aq1h_h, z1);
        z2 = MFMA16(bkh1, aq1l_h, z2);
        z3 = MFMA16(bkl1, aq1h_h, z3);
        sch[hh] = z1 + z2 + z3;
      }
      if (lact) {
        floatx4 z1 = {0.f, 0.f, 0.f, 0.f}, z2 = z1, z3 = z1;
        z1 = MFMA16(bkh0, aq0h_l, z1);
        z2 = MFMA16(bkh0, aq0l_l, z2);
        z3 = MFMA16(bkl0, aq0h_l, z3);
        z1 = MFMA16(bkh1, aq1h_l, z1);
        z2 = MFMA16(bkh1, aq1l_l, z2);
        z3 = MFMA16(bkl1, aq1h_l, z3);
        scl[hh] = z1 + z2 + z3;
      }
    }

    bf16x8 pah, pal;
    if (hact) pah = buildPA(sch, rfh, rsh, n0, m0h);
    if (lact) pal = buildPA(scl, rfl, rsl, n0, m0l);
    rfh *= gstep;
    if (nt + 1 < lt_ntiles) rfl *= gstep;

#pragma unroll
    for (int dt = 0; dt < 8; ++dt) {
      if (hact) oacch[dt] = MFMA16(pah, vv[dt], oacch[dt]);
      if (lact) oaccl[dt] = MFMA16(pal, vv[dt], oaccl[dt]);
    }
  };

  loadK(kA, 0);
  int nt = 0;
  while (true) {
    if (nt + 1 < ntiles) loadK(kB, nt + 1);
    body(kA, nt);
    if (++nt >= ntiles) break;
    if (nt + 1 < ntiles) loadK(kA, nt + 1);
    body(kB, nt);
    if (++nt >= ntiles) break;
  }

  // ---- epilogue: denom clip, groupnorm(128), silu gate — per stripe ----
  auto finalize = [&](floatx4* oacc, float rowsum, int m0) {
    float v = rowsum;
    v += __shfl_xor(v, 16);
    v += __shfl_xor(v, 32);
    float inv_den[4];
#pragma unroll
    for (int r = 0; r < 4; ++r) {
      float dsum = __shfl(v, quad * 4 + r);
      inv_den[r] = 1.0f / fmaxf(fabsf(dsum), 1.0f);
    }
    float s1[4] = {}, s2[4] = {};
#pragma unroll
    for (int dt = 0; dt < 8; ++dt) {
#pragma unroll
      for (int r = 0; r < 4; ++r) {
        float vv2 = oacc[dt][r] * inv_den[r];
        oacc[dt][r] = vv2;
        s1[r] += vv2;
        s2[r] += vv2 * vv2;
      }
    }
    float mean[4], istd[4];
#pragma unroll
    for (int r = 0; r < 4; ++r) {
      float a = s1[r], q2 = s2[r];
      a += __shfl_xor(a, 1); a += __shfl_xor(a, 2);
      a += __shfl_xor(a, 4); a += __shfl_xor(a, 8);
      q2 += __shfl_xor(q2, 1); q2 += __shfl_xor(q2, 2);
      q2 += __shfl_xor(q2, 4); q2 += __shfl_xor(q2, 8);
      mean[r] = a * (1.0f / 128.0f);
      float var = q2 * (1.0f / 128.0f) - mean[r] * mean[r];
      istd[r] = rsqrtf(fmaxf(var, 0.0f) + 1e-5f);
    }
#pragma unroll
    for (int dt = 0; dt < 8; ++dt) {
#pragma unroll
      for (int r = 0; r < 4; ++r) {
        int m = m0 + quad * 4 + r;
        int col = h * HD + dt * 16 + l16;
        float vv2 = (oacc[dt][r] - mean[r]) * istd[r];
        float gv = g[((size_t)b * SEQ + m) * 2048 + col];
        float sg = gv / (1.0f + expf(-gv));
        gated[((size_t)b * SEQ + m) * 2048 + col] = f2b(sg * vv2);
      }
    }
  };
  finalize(oacch, rsh, m0h);
  finalize(oaccl, rsl, m0l);
}

// ---------------- launch ----------------
extern "C" void kernel_launch(void* const* d_in, const int* in_sizes, int n_in,
                              void* d_out, int out_size, void* d_ws,
                              size_t ws_size, hipStream_t stream) {
  const float* x   = (const float*)d_in[0];
  const float* q_w = (const float*)d_in[1];
  const float* q_b = (const float*)d_in[2];
  const float* k_w = (const float*)d_in[3];
  const float* k_b = (const float*)d_in[4];
  const float* v_w = (const float*)d_in[5];
  const float* v_b = (const float*)d_in[6];
  const float* g_w = (const float*)d_in[7];
  const float* g_b = (const float*)d_in[8];
  const float* o_w = (const float*)d_in[9];
  const float* o_b = (const float*)d_in[10];

  char* ws = (char*)d_ws;
  bf16* Wt    = (bf16*)ws; ws += (size_t)6144 * 1024 * 2;
  bf16* oT    = (bf16*)ws; ws += (size_t)1024 * 2048 * 2;
  bf16* xb    = (bf16*)ws; ws += (size_t)4096 * 1024 * 2;
  float* Cqk  = (float*)ws; ws += (size_t)4096 * 2048 * 4;
  bf16* qhb   = (bf16*)ws; ws += (size_t)32 * 2048 * 64 * 2;
  bf16* qlb   = (bf16*)ws; ws += (size_t)32 * 2048 * 64 * 2;
  bf16* kfb   = (bf16*)ws; ws += (size_t)32 * 64 * 8 * 512 * 2;  // 16.78 MB (K hi+lo frags)
  bf16* vfb   = (bf16*)ws; ws += (size_t)32 * 64 * 8 * 512 * 2;  // 16.78 MB (V frags)
  float* gbuf = (float*)ws; ws += (size_t)2 * 2048 * 2048 * 4;
  bf16* gated = (bf16*)ws; ws += (size_t)4096 * 2048 * 2;
  // vbuf aliases gated: vbuf lives GEMM1->vtrans, gated lives retention->GEMM2
  bf16* vbuf  = gated;

  convert_k<<<(4096 * 1024 / 4) / 256, 256, 0, stream>>>(x, xb);

  dim3 tb(32, 8);
  transpose_k<<<dim3(1024 / 32, 1024 / 32), tb, 0, stream>>>(q_w, Wt, 1024, 1024);
  transpose_k<<<dim3(1024 / 32, 1024 / 32), tb, 0, stream>>>(k_w, Wt + (size_t)1024 * 1024, 1024, 1024);
  transpose_k<<<dim3(2048 / 32, 1024 / 32), tb, 0, stream>>>(v_w, Wt + (size_t)2048 * 1024, 1024, 2048);
  transpose_k<<<dim3(2048 / 32, 1024 / 32), tb, 0, stream>>>(g_w, Wt + (size_t)4096 * 1024, 1024, 2048);
  transpose_k<<<dim3(1024 / 32, 2048 / 32), tb, 0, stream>>>(o_w, oT, 2048, 1024);

  gemm_bt<128, 128, 1024, 0><<<dim3(6144 / 128, 4096 / 128), 256, 0, stream>>>(
      xb, Wt, 6144, q_b, k_b, v_b, g_b, Cqk, vbuf, gbuf, nullptr);

  vtrans_k<<<dim3(2048 / 32, 2048 / 64, B_SZ), tb, 0, stream>>>(vbuf, vfb);

  router_k<<<(4096 * 1024) / 256, 256, 0, stream>>>(Cqk, qhb, qlb, kfb);

  retention_k<<<dim3(1024), 128, 0, stream>>>(
      qhb, qlb, kfb, vfb, gbuf, gated);

  gemm_bt<128, 64, 2048, 1><<<dim3(1024 / 64, 4096 / 128), 256, 0, stream>>>(
      gated, oT, 1024, o_b, nullptr, nullptr, nullptr, nullptr, nullptr,
      nullptr, (float*)d_out);
}

// Round 7
// 333.119 us; speedup vs baseline: 1.0731x; 1.0731x over previous
//
#include <hip/hip_runtime.h>
#include <hip/hip_bf16.h>

// MultiScaleRetention forward. Inputs/outputs FLOAT32; internals bf16 MFMA.
//   0) convert x -> xb (bf16); transpose weights f32 -> bf16
//   1) GEMM1 (m97-style, global_load_lds staging): xb @ Wt^T; LEAN epilogue,
//      ALL-COALESCED: qk -> f32 Cqk (+bias,+k-scale); V -> bf16 directly in
//      FRAGMENT layout (vtrans kernel deleted; R17); g -> f32
//   2) router: rotary (f32) + hi/lo bf16 split + (bh,S,64) layout for q,k
//      (R12 version)
//   3) retention = R15 EXACT (proven 105.9us): LDS-staged K hi/lo
//      (double-buffered ASYNC16), paired 32-row half-stripes, swapped QK +
//      permlane P, V direct global->reg from fragment buffer.
//      R16 lesson: K direct-to-reg (zero-LDS) regressed (2x K read traffic,
//      FETCH 206->292MB, 105.9->111.2us) -> LDS K-staging is net-positive.
//      Occupancy is grid-capped (2048 waves total = 2/SIMD); raising it
//      needs K-range splitting (breaks canary) - future work.
//   4) GEMM2: gated @ oT^T + o_b -> d_out (f32)
//
// V values bit-identical to the old vbuf->vtrans path -> absmax must stay
// exactly 0.01049805 (canary).

typedef __hip_bfloat16 bf16;
typedef short bf16x4 __attribute__((ext_vector_type(4)));
typedef short bf16x8 __attribute__((ext_vector_type(8)));
typedef float floatx4 __attribute__((ext_vector_type(4)));

#define B_SZ 2
#define SEQ 2048
#define NH 16
#define KD 64
#define HD 128

// global->LDS direct copy, 16B/lane. LDS dest is wave-uniform base + lane*16.
#define ASYNC16(gp, lp)                                                             \
  __builtin_amdgcn_global_load_lds(                                                 \
      (const __attribute__((address_space(1))) unsigned int*)(unsigned long long)(const void*)(gp), \
      (__attribute__((address_space(3))) unsigned int*)(unsigned int)(unsigned long long)(void*)(lp), \
      16, 0, 0)

__device__ __forceinline__ float b2f(bf16 x) { return __bfloat162float(x); }
__device__ __forceinline__ bf16 f2b(float x) { return __float2bfloat16(x); }

#define MFMA16(a, bb, c) __builtin_amdgcn_mfma_f32_16x16x32_bf16(a, bb, c, 0, 0, 0)

// ---------------- f32 -> bf16 convert (x) ----------------
__global__ void convert_k(const float* __restrict__ in, bf16* __restrict__ out) {
  int i = blockIdx.x * 256 + threadIdx.x;  // one float4 per thread
  float4 v = reinterpret_cast<const float4*>(in)[i];
  union { bf16 h[4]; bf16x4 v4; } u;
  u.h[0] = f2b(v.x); u.h[1] = f2b(v.y); u.h[2] = f2b(v.z); u.h[3] = f2b(v.w);
  reinterpret_cast<bf16x4*>(out)[i] = u.v4;
}

// ---------------- weight transpose: in f32 (K,N) -> out bf16 (N,K) --------
__global__ void transpose_k(const float* __restrict__ in, bf16* __restrict__ out,
                            int K, int N) {
  __shared__ float tile[32][33];
  int tx = threadIdx.x, ty = threadIdx.y;
  int n0 = blockIdx.x * 32, k0 = blockIdx.y * 32;
#pragma unroll
  for (int j = 0; j < 4; ++j)
    tile[ty + j * 8][tx] = in[(size_t)(k0 + ty + j * 8) * N + n0 + tx];
  __syncthreads();
#pragma unroll
  for (int j = 0; j < 4; ++j)
    out[(size_t)(n0 + ty + j * 8) * K + k0 + tx] = f2b(tile[tx][ty + j * 8]);
}

// ---------------- GEMM: C(M,N) = A(M,K) @ Bt(N,K)^T ----------------
// MODE 0: fused epilogue. qk cols -> f32 Cqk (+bias, k-scale). V cols ->
// bf16 FRAGMENT layout (chunk=(bh*64+nt)*8+dt; elem=(srun*16+lw)*8+k holds
// V[s=nt*32+srun*8+k][d=dt*16+lw]) -- one 8B store per (i,j), wave-coalesced
// (quads 0+1 / 2+3 tile contiguous 256B spans). g cols -> f32.
template <int BM, int BN, int KDIM, int MODE>
__global__ __launch_bounds__(256, 2) void gemm_bt(
    const bf16* __restrict__ A, const bf16* __restrict__ Bt, int Ndim,
    const float* __restrict__ bias_q, const float* __restrict__ bias_k,
    const float* __restrict__ bias_v, const float* __restrict__ bias_g,
    float* __restrict__ outCqk, bf16* __restrict__ out_v,
    float* __restrict__ out_g, float* __restrict__ outF) {
  __shared__ bf16 As[BM * 32];
  __shared__ bf16 Bs[BN * 32];
  const int tid = threadIdx.x;
  const int wave = tid >> 6, lane = tid & 63;
  const int quad = lane >> 4, l16 = lane & 15;
  const int m0 = blockIdx.y * BM, n0 = blockIdx.x * BN;
  constexpr int FI = BM / 32;
  constexpr int FJ = BN / 32;
  const int wm = (wave >> 1) * (BM / 2), wn = (wave & 1) * (BN / 2);

  floatx4 acc[FI][FJ] = {};

  for (int k0 = 0; k0 < KDIM; k0 += 32) {
#pragma unroll
    for (int j = 0; j < BM / 64; ++j) {
      int cbase = (j * 4 + wave) * 64;
      int c = cbase + lane;
      const bf16* g = A + (size_t)(m0 + (c >> 2)) * KDIM + k0 + (c & 3) * 8;
      ASYNC16(g, &As[cbase * 8]);
    }
#pragma unroll
    for (int j = 0; j < BN / 64; ++j) {
      int cbase = (j * 4 + wave) * 64;
      int c = cbase + lane;
      const bf16* g = Bt + (size_t)(n0 + (c >> 2)) * KDIM + k0 + (c & 3) * 8;
      ASYNC16(g, &Bs[cbase * 8]);
    }
    __syncthreads();  // compiler drains vmcnt(0) before s_barrier

    bf16x8 af[FI], bfr[FJ];
#pragma unroll
    for (int i = 0; i < FI; ++i)
      af[i] = *(const bf16x8*)&As[(wm + i * 16 + l16) * 32 + quad * 8];
#pragma unroll
    for (int j = 0; j < FJ; ++j)
      bfr[j] = *(const bf16x8*)&Bs[(wn + j * 16 + l16) * 32 + quad * 8];
#pragma unroll
    for (int i = 0; i < FI; ++i)
#pragma unroll
      for (int j = 0; j < FJ; ++j)
        acc[i][j] = MFMA16(af[i], bfr[j], acc[i][j]);
    __syncthreads();
  }

  // LEAN epilogue, all stores coalesced
#pragma unroll
  for (int i = 0; i < FI; ++i) {
#pragma unroll
    for (int j = 0; j < FJ; ++j) {
      int gn = n0 + wn + j * 16 + l16;
      if (MODE == 0 && gn >= 2048 && gn < 4096) {
        // V -> fragment layout, one 8B packed store (4 consecutive s)
        int jj = gn - 2048;
        int s0 = m0 + wm + i * 16 + quad * 4;  // 4-aligned
        union { bf16 e[4]; unsigned long long u8; } pk;
#pragma unroll
        for (int r = 0; r < 4; ++r) pk.e[r] = f2b(acc[i][j][r] + bias_v[jj]);
        int b2 = s0 >> 11, srel = s0 & 2047;
        int h2 = jj >> 7, dloc = jj & 127;
        size_t bh2 = (size_t)b2 * NH + h2;
        size_t idx = ((bh2 * 64 + (srel >> 5)) * 8 + (dloc >> 4)) * 512 +
                     (size_t)(((srel >> 3) & 3) * 16 + (dloc & 15)) * 8 +
                     (srel & 7);
        *(unsigned long long*)&out_v[idx] = pk.u8;
      } else {
#pragma unroll
        for (int r = 0; r < 4; ++r) {
          int gm = m0 + wm + i * 16 + quad * 4 + r;
          float v = acc[i][j][r];
          if (MODE == 1) {
            v += bias_q[gn];  // bias_q = o_b
            outF[(size_t)gm * Ndim + gn] = v;
          } else {
            if (gn < 2048) {
              bool is_k = gn >= 1024;
              int jj = is_k ? gn - 1024 : gn;
              v += is_k ? bias_k[jj] : bias_q[jj];
              if (is_k) v *= 0.125f;  // SCALING = KEY_DIM^-0.5
              outCqk[(size_t)gm * 2048 + gn] = v;  // f32, exact
            } else {
              int jj = gn - 4096;
              v += bias_g[jj];
              out_g[(size_t)gm * 2048 + jj] = v;  // f32
            }
          }
        }
      }
    }
  }
}

// ---------------- router: rotary + hi/lo split + layout (R12 version) -----
__global__ void router_k(const float* __restrict__ Cqk,
                         bf16* __restrict__ qh, bf16* __restrict__ ql,
                         bf16* __restrict__ kh, bf16* __restrict__ kl) {
  int t = blockIdx.x * 256 + threadIdx.x;  // 4096*1024 threads
  int row = t >> 10, pc = t & 1023;
  int b = row >> 11, s = row & 2047;
  bool is_k = pc >= 512;
  int jj = (pc - (is_k ? 512 : 0)) * 2;  // even, 0..1022
  int h = jj >> 6, d = jj & 63, ii = d >> 1;
  float2 v = *(const float2*)&Cqk[(size_t)row * 2048 + pc * 2];
  float half = exp2f(-(float)ii * (13.287712379549449f / 31.0f));
  float ang = (float)s * half;
  float sn = sinf(ang), cs = cosf(ang);
  float e = v.x * cs - v.y * sn;
  float o = v.y * cs + v.x * sn;
  bf16 eh = f2b(e), oh = f2b(o);
  bf16 el = f2b(e - b2f(eh)), ol = f2b(o - b2f(oh));
  size_t idx = (((size_t)b * NH + h) * SEQ + s) * KD + d;
  bf16* ph = is_k ? kh : qh;
  bf16* pl = is_k ? kl : ql;
  union { bf16 h2[2]; unsigned u; } uh, ul;
  uh.h2[0] = eh; uh.h2[1] = oh;
  ul.h2[0] = el; ul.h2[1] = ol;
  *(unsigned*)&ph[idx] = uh.u;
  *(unsigned*)&pl[idx] = ul.u;
}

// ---------------- retention core (R15 EXACT: R12 + V direct-to-reg) -------
// grid 1024 flat; bid -> (seg = bid>>5 -> h=seg&15, b=seg>>4), px_raw=bid&31.
// px = (seg bit3) ? 31-px_raw : px_raw. Block px owns TWO 32-row
// half-stripes: heavy bt_h=63-px, light bt_l=px. QK swapped (A=K, B=Q),
// P rebuilt in-register via permlane. K hi/lo staged in LDS (double-buffered,
// 4 chunks/wave); V loaded per-tile straight to registers from the
// fragment-ordered vf buffer (8 x global_load_dwordx4, coalesced).
__global__ __launch_bounds__(128, 2) void retention_k(
    const bf16* __restrict__ qh, const bf16* __restrict__ ql,
    const bf16* __restrict__ kh, const bf16* __restrict__ kl,
    const bf16* __restrict__ vf, const float* __restrict__ g,
    bf16* __restrict__ gated) {
  __shared__ bf16 KHs[2][32 * 64];
  __shared__ bf16 KLs[2][32 * 64];
  const int tid = threadIdx.x;
  const int wave = tid >> 6, lane = tid & 63;
  const int quad = lane >> 4, l16 = lane & 15;
  const int bid = blockIdx.x;
  const int px_raw = bid & 31;
  const int seg = bid >> 5;           // 0..31
  const int h = seg & 15, b = seg >> 4;
  const int px = ((seg >> 3) & 1) ? (31 - px_raw) : px_raw;
  const int bh = b * NH + h;
  const int bt_h = 63 - px;           // heavy half-stripe (32 rows)
  const int bt_l = px;                // light half-stripe
  const int m0h = bt_h * 32 + wave * 16;
  const int m0l = bt_l * 32 + wave * 16;
  const int ntiles = bt_h + 1;
  const int lt_ntiles = bt_l + 1;

  const float t = exp2f(-(float)(5 + h));  // 1-gamma (exact)
  const float lng = log1pf(-t);            // ln(gamma)
  const float log2g = lng * 1.44269504088896340736f;

  // per-lane row scalars (m = m0 + l16)
  float rfh, rfl;
  {
    int mh = m0h + l16, ml = m0l + l16;
    rfh = exp2f((float)mh * log2g) *
          rsqrtf(-expm1f((float)(mh + 1) * lng) / t);
    rfl = exp2f((float)ml * log2g) *
          rsqrtf(-expm1f((float)(ml + 1) * lng) / t);
  }
  const float gstep = exp2f(-32.0f * log2g);  // gamma^-32
  // per-lane col decay: n-offset = hh*16 + quad*4 + r
  float cfq[8];
#pragma unroll
  for (int i = 0; i < 8; ++i) {
    int hh = i >> 2, r = i & 3;
    cfq[i] = exp2f(-(float)(hh * 16 + quad * 4 + r) * log2g);
  }

  const size_t qoffh = ((size_t)bh * SEQ + m0h + l16) * KD;
  const size_t qoffl = ((size_t)bh * SEQ + m0l + l16) * KD;
  bf16x8 aq0h_h = *(const bf16x8*)&qh[qoffh + quad * 8];
  bf16x8 aq1h_h = *(const bf16x8*)&qh[qoffh + 32 + quad * 8];
  bf16x8 aq0l_h = *(const bf16x8*)&ql[qoffh + quad * 8];
  bf16x8 aq1l_h = *(const bf16x8*)&ql[qoffh + 32 + quad * 8];
  bf16x8 aq0h_l = *(const bf16x8*)&qh[qoffl + quad * 8];
  bf16x8 aq1h_l = *(const bf16x8*)&qh[qoffl + 32 + quad * 8];
  bf16x8 aq0l_l = *(const bf16x8*)&ql[qoffl + quad * 8];
  bf16x8 aq1l_l = *(const bf16x8*)&ql[qoffl + 32 + quad * 8];

  floatx4 oacch[8] = {}, oaccl[8] = {};
  float rsh = 0.f, rsl = 0.f;

  const bf16* khb = kh + (size_t)bh * SEQ * KD;
  const bf16* klb = kl + (size_t)bh * SEQ * KD;
  const bf16* vfb = vf + (size_t)bh * 64 * 8 * 512;
  const int lo8 = lane * 8;

  // K staging: 8 x 1KB chunks per tile over 2 waves (4 each):
  // wave0 -> KH (cc 0..3), wave1 -> KL (cc 4..7). Same swizzle as R12.
  auto stage = [&](int nt, int buf) {
    const int n0s = nt * 32;
#pragma unroll
    for (int j = 0; j < 4; ++j) {
      int cc = wave * 4 + j;
      const bf16* src = (cc < 4) ? khb : klb;
      bf16* dst = (cc < 4) ? KHs[buf] : KLs[buf];
      int r = ((cc & 3) * 8) + (lane >> 3);
      int s = lane & 7;
      int q = (s - r) & 7;
      ASYNC16(src + (size_t)(n0s + r) * KD + q * 8, &dst[(cc & 3) * 512]);
    }
  };

  // Build PV A-frag in-register from the transposed score tile (as R12).
  auto buildPA = [&](const floatx4* sc, float rf, float& rs, int n0,
                     int m0) -> bf16x8 {
    const int m = m0 + l16;
    const bool full = (m0 >= n0 + 31);  // tile fully below diagonal
    unsigned d[4];
#pragma unroll
    for (int hh = 0; hh < 2; ++hh) {
      float p[4];
#pragma unroll
      for (int r = 0; r < 4; ++r) {
        float pv;
        if (full) {
          pv = sc[hh][r] * rf * cfq[hh * 4 + r];
        } else {
          int n = n0 + hh * 16 + quad * 4 + r;
          pv = (m >= n) ? sc[hh][r] * rf * cfq[hh * 4 + r] : 0.f;
        }
        rs += pv;
        p[r] = pv;
      }
      union { bf16 hx[2]; unsigned u; } u0, u1;
      u0.hx[0] = f2b(p[0]); u0.hx[1] = f2b(p[1]);
      u1.hx[0] = f2b(p[2]); u1.hx[1] = f2b(p[3]);
      d[hh * 2 + 0] = u0.u;
      d[hh * 2 + 1] = u1.u;
    }
    unsigned a0 = d[0], b0 = d[2];  // (hh0 pair01, hh1 pair01)
    asm("v_permlane32_swap_b32 %0, %1" : "+v"(a0), "+v"(b0));
    asm("v_permlane16_swap_b32 %0, %1" : "+v"(a0), "+v"(b0));
    unsigned a1 = d[1], b1 = d[3];  // (hh0 pair23, hh1 pair23)
    asm("v_permlane32_swap_b32 %0, %1" : "+v"(a1), "+v"(b1));
    asm("v_permlane16_swap_b32 %0, %1" : "+v"(a1), "+v"(b1));
    union { unsigned u[4]; bf16x8 v; } pu;
    pu.u[0] = a0; pu.u[1] = a1; pu.u[2] = b0; pu.u[3] = b1;
    return pu.v;
  };

  stage(0, 0);
  for (int nt = 0; nt < ntiles; ++nt) {
    const int n0 = nt * 32;
    const int cur = nt & 1;
    asm volatile("s_waitcnt vmcnt(0) lgkmcnt(0)" ::: "memory");
    __syncthreads();

    // ---- V tile direct to registers (coalesced dwordx4; latency hides
    // under QK/buildPA; compiler's counted vmcnt keeps stage loads async) ----
    bf16x8 vv[8];
#pragma unroll
    for (int c = 0; c < 8; ++c)
      vv[c] = *(const bf16x8*)(vfb + ((size_t)nt * 8 + c) * 512 + lo8);

    {
      int pf = (nt + 1 < ntiles) ? nt + 1 : nt;
      stage(pf, cur ^ 1);
    }

    const bool hact = (n0 <= m0h + 15);
    const bool lact = (n0 <= m0l + 15);

    // ---- QK (SWAPPED: A=K-frag, B=Q-frag) for both stripes, sharing K ----
    floatx4 sch[2], scl[2];
#pragma unroll
    for (int hh = 0; hh < 2; ++hh) {
      int krow = hh * 16 + l16;
      int c0 = ((quad + krow) & 7) * 8;
      int c1 = ((quad + 4 + krow) & 7) * 8;
      bf16x8 bkh0 = *(const bf16x8*)&KHs[cur][krow * 64 + c0];
      bf16x8 bkh1 = *(const bf16x8*)&KHs[cur][krow * 64 + c1];
      bf16x8 bkl0 = *(const bf16x8*)&KLs[cur][krow * 64 + c0];
      bf16x8 bkl1 = *(const bf16x8*)&KLs[cur][krow * 64 + c1];
      if (hact) {
        floatx4 z1 = {0.f, 0.f, 0.f, 0.f}, z2 = z1, z3 = z1;
        z1 = MFMA16(bkh0, aq0h_h, z1);
        z2 = MFMA16(bkh0, aq0l_h, z2);
        z3 = MFMA16(bkl0, aq0h_h, z3);
        z1 = MFMA16(bkh1, aq1h_h, z1);
        z2 = MFMA16(bkh1, aq1l_h, z2);
        z3 = MFMA16(bkl1, aq1h_h, z3);
        sch[hh] = z1 + z2 + z3;
      }
      if (lact) {
        floatx4 z1 = {0.f, 0.f, 0.f, 0.f}, z2 = z1, z3 = z1;
        z1 = MFMA16(bkh0, aq0h_l, z1);
        z2 = MFMA16(bkh0, aq0l_l, z2);
        z3 = MFMA16(bkl0, aq0h_l, z3);
        z1 = MFMA16(bkh1, aq1h_l, z1);
        z2 = MFMA16(bkh1, aq1l_l, z2);
        z3 = MFMA16(bkl1, aq1h_l, z3);
        scl[hh] = z1 + z2 + z3;
      }
    }

    // ---- decay mask + row sums + PA rebuild, all in-register ----
    bf16x8 pah, pal;
    if (hact) pah = buildPA(sch, rfh, rsh, n0, m0h);
    if (lact) pal = buildPA(scl, rfl, rsl, n0, m0l);
    rfh *= gstep;
    if (nt + 1 < lt_ntiles) rfl *= gstep;

    // ---- PV for both stripes, sharing V registers ----
#pragma unroll
    for (int dt = 0; dt < 8; ++dt) {
      if (hact) oacch[dt] = MFMA16(pah, vv[dt], oacch[dt]);
      if (lact) oaccl[dt] = MFMA16(pal, vv[dt], oaccl[dt]);
    }
  }

  // ---- epilogue: denom clip, groupnorm(128), silu gate — per stripe ----
  auto finalize = [&](floatx4* oacc, float rowsum, int m0) {
    float v = rowsum;
    v += __shfl_xor(v, 16);
    v += __shfl_xor(v, 32);
    float inv_den[4];
#pragma unroll
    for (int r = 0; r < 4; ++r) {
      float dsum = __shfl(v, quad * 4 + r);
      inv_den[r] = 1.0f / fmaxf(fabsf(dsum), 1.0f);
    }
    float s1[4] = {}, s2[4] = {};
#pragma unroll
    for (int dt = 0; dt < 8; ++dt) {
#pragma unroll
      for (int r = 0; r < 4; ++r) {
        float vv2 = oacc[dt][r] * inv_den[r];
        oacc[dt][r] = vv2;
        s1[r] += vv2;
        s2[r] += vv2 * vv2;
      }
    }
    float mean[4], istd[4];
#pragma unroll
    for (int r = 0; r < 4; ++r) {
      float a = s1[r], q2 = s2[r];
      a += __shfl_xor(a, 1); a += __shfl_xor(a, 2);
      a += __shfl_xor(a, 4); a += __shfl_xor(a, 8);
      q2 += __shfl_xor(q2, 1); q2 += __shfl_xor(q2, 2);
      q2 += __shfl_xor(q2, 4); q2 += __shfl_xor(q2, 8);
      mean[r] = a * (1.0f / 128.0f);
      float var = q2 * (1.0f / 128.0f) - mean[r] * mean[r];
      istd[r] = rsqrtf(fmaxf(var, 0.0f) + 1e-5f);
    }
#pragma unroll
    for (int dt = 0; dt < 8; ++dt) {
#pragma unroll
      for (int r = 0; r < 4; ++r) {
        int m = m0 + quad * 4 + r;
        int col = h * HD + dt * 16 + l16;
        float vv2 = (oacc[dt][r] - mean[r]) * istd[r];
        float gv = g[((size_t)b * SEQ + m) * 2048 + col];
        float sg = gv / (1.0f + expf(-gv));
        gated[((size_t)b * SEQ + m) * 2048 + col] = f2b(sg * vv2);
      }
    }
  };
  finalize(oacch, rsh, m0h);
  finalize(oaccl, rsl, m0l);
}

// ---------------- launch ----------------
extern "C" void kernel_launch(void* const* d_in, const int* in_sizes, int n_in,
                              void* d_out, int out_size, void* d_ws,
                              size_t ws_size, hipStream_t stream) {
  const float* x   = (const float*)d_in[0];
  const float* q_w = (const float*)d_in[1];
  const float* q_b = (const float*)d_in[2];
  const float* k_w = (const float*)d_in[3];
  const float* k_b = (const float*)d_in[4];
  const float* v_w = (const float*)d_in[5];
  const float* v_b = (const float*)d_in[6];
  const float* g_w = (const float*)d_in[7];
  const float* g_b = (const float*)d_in[8];
  const float* o_w = (const float*)d_in[9];
  const float* o_b = (const float*)d_in[10];

  char* ws = (char*)d_ws;
  bf16* Wt    = (bf16*)ws; ws += (size_t)6144 * 1024 * 2;
  bf16* oT    = (bf16*)ws; ws += (size_t)1024 * 2048 * 2;
  bf16* xb    = (bf16*)ws; ws += (size_t)4096 * 1024 * 2;
  float* Cqk  = (float*)ws; ws += (size_t)4096 * 2048 * 4;
  bf16* qhb   = (bf16*)ws; ws += (size_t)32 * 2048 * 64 * 2;
  bf16* qlb   = (bf16*)ws; ws += (size_t)32 * 2048 * 64 * 2;
  bf16* khb   = (bf16*)ws; ws += (size_t)32 * 2048 * 64 * 2;
  bf16* klb   = (bf16*)ws; ws += (size_t)32 * 2048 * 64 * 2;
  bf16* vfb   = (bf16*)ws; ws += (size_t)32 * 64 * 8 * 512 * 2;  // 16.78 MB V frags
  float* gbuf = (float*)ws; ws += (size_t)2 * 2048 * 2048 * 4;
  bf16* gated = (bf16*)ws; ws += (size_t)4096 * 2048 * 2;

  convert_k<<<(4096 * 1024 / 4) / 256, 256, 0, stream>>>(x, xb);

  dim3 tb(32, 8);
  transpose_k<<<dim3(1024 / 32, 1024 / 32), tb, 0, stream>>>(q_w, Wt, 1024, 1024);
  transpose_k<<<dim3(1024 / 32, 1024 / 32), tb, 0, stream>>>(k_w, Wt + (size_t)1024 * 1024, 1024, 1024);
  transpose_k<<<dim3(2048 / 32, 1024 / 32), tb, 0, stream>>>(v_w, Wt + (size_t)2048 * 1024, 1024, 2048);
  transpose_k<<<dim3(2048 / 32, 1024 / 32), tb, 0, stream>>>(g_w, Wt + (size_t)4096 * 1024, 1024, 2048);
  transpose_k<<<dim3(1024 / 32, 2048 / 32), tb, 0, stream>>>(o_w, oT, 2048, 1024);

  // GEMM1 writes V directly in fragment layout (vtrans fused away)
  gemm_bt<128, 128, 1024, 0><<<dim3(6144 / 128, 4096 / 128), 256, 0, stream>>>(
      xb, Wt, 6144, q_b, k_b, v_b, g_b, Cqk, vfb, gbuf, nullptr);

  router_k<<<(4096 * 1024) / 256, 256, 0, stream>>>(Cqk, qhb, qlb, khb, klb);

  retention_k<<<dim3(1024), 128, 0, stream>>>(
      qhb, qlb, khb, klb, vfb, gbuf, gated);

  gemm_bt<128, 64, 2048, 1><<<dim3(1024 / 64, 4096 / 128), 256, 0, stream>>>(
      gated, oT, 1024, o_b, nullptr, nullptr, nullptr, nullptr, nullptr,
      nullptr, (float*)d_out);
}